// Round 8
// baseline (148.863 us; speedup 1.0000x reference)
//
#include <hip/hip_runtime.h>
#include <math.h>

#define BATCH  8
#define SEQ    1024
#define DMODEL 512
#define NHEADS 8
#define DHEAD  64
#define MTOT   (BATCH*SEQ)      // 8192
#define QKVLD  (3*DMODEL)       // 1536

typedef unsigned short ushortT;
typedef __attribute__((ext_vector_type(8))) short short8;
typedef __attribute__((ext_vector_type(4))) float f32x4;

typedef __attribute__((address_space(3))) unsigned char lds_byte;
typedef __attribute__((address_space(1))) const unsigned char glob_byte;

__device__ inline void g2l16(const void* g, void* l) {
    __builtin_amdgcn_global_load_lds((glob_byte*)g, (lds_byte*)l, 16, 0, 0);
}

__device__ inline ushortT f2bf(float f) {            // round-to-nearest
    union { float f; unsigned u; } v; v.f = f;
    unsigned r = (v.u + 0x7FFFu + ((v.u >> 16) & 1u)) >> 16;
    return (ushortT)r;
}
__device__ inline ushortT f2bf_fast(float f) {       // round-half-up (2 ops)
    union { float f; unsigned u; } v; v.f = f;
    return (ushortT)((v.u + 0x8000u) >> 16);
}

// ---------------------------------------------------------------------------
// All input conversions in ONE launch.
// blocks 0..2047:    x fp32 -> x_bf (8 elems/thread)
// blocks 2048..2815: w_qkv [512][1536] -> wqkvT [1536][512]
// blocks 2816..3071: w_out [512][512] -> woutT [512][512]
// ---------------------------------------------------------------------------
__global__ __launch_bounds__(256)
void cvt_all(const float* __restrict__ x, ushortT* __restrict__ x_bf,
             const float* __restrict__ Wq, ushortT* __restrict__ WqT,
             const float* __restrict__ Wo, ushortT* __restrict__ WoT)
{
    __shared__ float T[32][33];
    const int t = threadIdx.x;
    int bid = blockIdx.x;
    if (bid < 2048) {
        const int gid = bid * 256 + t;
        const float4 a = *(const float4*)(x + (long)gid*8);
        const float4 b = *(const float4*)(x + (long)gid*8 + 4);
        ushortT o[8];
        o[0]=f2bf(a.x); o[1]=f2bf(a.y); o[2]=f2bf(a.z); o[3]=f2bf(a.w);
        o[4]=f2bf(b.x); o[5]=f2bf(b.y); o[6]=f2bf(b.z); o[7]=f2bf(b.w);
        *(short8*)(x_bf + (long)gid*8) = *(short8*)o;
        return;
    }
    bid -= 2048;
    const float* W; ushortT* WT; int N, n0, k0;
    if (bid < 768) { W = Wq; WT = WqT; N = QKVLD;  n0 = (bid % 48) * 32; k0 = (bid / 48) * 32; }
    else { bid -= 768; W = Wo; WT = WoT; N = DMODEL; n0 = (bid % 16) * 32; k0 = (bid / 16) * 32; }
    const int K = DMODEL;
    {
        const int r = t >> 3, c4 = (t & 7) * 4;
        const float4 v = *(const float4*)(W + (long)(k0 + r)*N + n0 + c4);
        T[c4+0][r] = v.x; T[c4+1][r] = v.y; T[c4+2][r] = v.z; T[c4+3][r] = v.w;
    }
    __syncthreads();
    {
        const int n = t >> 3, k4 = (t & 7) * 4;
        ushortT o[4];
        o[0] = f2bf(T[n][k4+0]); o[1] = f2bf(T[n][k4+1]);
        o[2] = f2bf(T[n][k4+2]); o[3] = f2bf(T[n][k4+3]);
        *(uint2*)(WT + (long)(n0 + n)*K + k0 + k4) = *(uint2*)o;
    }
}

// ---------------------------------------------------------------------------
// bf16 MFMA GEMM: C[M][N] = A[M][K] * BT[N][K]^T
// 128x128 tile, BK=64, 256 thr (2x2 waves), global_load_lds width-16,
// 3-bit XOR swizzle on global source + ds_read side (rule 21).
// DOUBLE-BUFFERED (T3-minimal): issue next tile's global_load_lds BEFORE
// computing the current tile; one vmcnt(0)+barrier per K-step (stage
// latency hides under ~700cy of MFMA). LDS 64KB -> 2 blocks/CU.
// MODE 0: fp32 C out.
// MODE 1 (qkv): bf16 C; Q cols (bn<4) pre-scaled by exp(temp)*log2e;
//   V cols (bn>=8) written ONLY to vT[b,h][d][n] (transposed).
// ---------------------------------------------------------------------------
template <int MODE>
__global__ __launch_bounds__(256, 2)
void gemm_bf16(const ushortT* __restrict__ A, const ushortT* __restrict__ BT,
               void* __restrict__ Cv, ushortT* __restrict__ vT,
               const float* __restrict__ temp, int M, int N, int K)
{
    __shared__ ushortT As[2][128*64];   // 32 KB
    __shared__ ushortT Bs[2][128*64];   // 32 KB

    const int t    = threadIdx.x;
    const int lane = t & 63;
    const int w    = t >> 6;
    const int l15  = lane & 15, l4 = lane >> 4;

    const int nwg = gridDim.x * gridDim.y;
    const int bid = blockIdx.y * gridDim.x + blockIdx.x;
    const int swz = (bid & 7) * (nwg >> 3) + (bid >> 3);
    const int bm  = swz / gridDim.x;
    const int bn  = swz % gridDim.x;

    const int srow = t >> 3;     // 0..31
    const int slot = t & 7;      // 0..7 (16B slots in a 128B row)

    f32x4 acc[4][4] = {};
    const int NK = K >> 6;

    // ---- prologue: stage tile 0 ----
#pragma unroll
    for (int c = 0; c < 4; ++c) {
        const int row  = c*32 + srow;
        const int scol = ((slot ^ (row & 7)) << 4);   // bytes
        g2l16((const char*)(A  + (long)(bm*128 + row)*K) + scol,
              (char*)&As[0][0] + c*4096 + t*16);
        g2l16((const char*)(BT + (long)(bn*128 + row)*K) + scol,
              (char*)&Bs[0][0] + c*4096 + t*16);
    }
    asm volatile("s_waitcnt vmcnt(0)" ::: "memory");
    __syncthreads();

    for (int it = 0; it < NK; ++it) {
        const int cur = it & 1;

        // ---- issue next tile's staging (hidden under compute) ----
        if (it + 1 < NK) {
            const int kt = (it + 1) << 6;
#pragma unroll
            for (int c = 0; c < 4; ++c) {
                const int row  = c*32 + srow;
                const int scol = ((slot ^ (row & 7)) << 4);
                g2l16((const char*)(A  + (long)(bm*128 + row)*K + kt) + scol,
                      (char*)&As[cur^1][0] + c*4096 + t*16);
                g2l16((const char*)(BT + (long)(bn*128 + row)*K + kt) + scol,
                      (char*)&Bs[cur^1][0] + c*4096 + t*16);
            }
        }

        const ushortT* Ac = &As[cur][0];
        const ushortT* Bc = &Bs[cur][0];
#pragma unroll
        for (int kk = 0; kk < 2; ++kk) {
            short8 a[4], b[4];
#pragma unroll
            for (int i = 0; i < 4; ++i) {
                const int ra = (w >> 1)*64 + i*16 + l15;
                const int ca = (kk*32 + l4*8) ^ ((ra & 7) << 3);
                a[i] = *(const short8*)&Ac[ra*64 + ca];
                const int rb = (w & 1)*64 + i*16 + l15;
                const int cb = (kk*32 + l4*8) ^ ((rb & 7) << 3);
                b[i] = *(const short8*)&Bc[rb*64 + cb];
            }
#pragma unroll
            for (int i = 0; i < 4; ++i)
#pragma unroll
                for (int j = 0; j < 4; ++j)
                    acc[i][j] = __builtin_amdgcn_mfma_f32_16x16x32_bf16(
                                    a[i], b[j], acc[i][j], 0, 0, 0);
        }

        // ---- drain next-tile staging, single barrier ----
        asm volatile("s_waitcnt vmcnt(0)" ::: "memory");
        __syncthreads();
    }

    if (MODE == 1 && bn >= 8) {
        // V columns -> vT[(b*8+h)*64 + d][n], packed 4x bf16 along n
#pragma unroll
        for (int i = 0; i < 4; ++i) {
            const int row0 = bm*128 + (w >> 1)*64 + i*16 + l4*4;
            const int bb   = row0 >> 10, n = row0 & 1023;
#pragma unroll
            for (int j = 0; j < 4; ++j) {
                const int cg = bn*128 + (w & 1)*64 + j*16 + l15 - 1024; // 0..511
                const int h = cg >> 6, d = cg & 63;
                union { ushortT u[4]; uint2 q; } pk;
#pragma unroll
                for (int r = 0; r < 4; ++r) pk.u[r] = f2bf(acc[i][j][r]);
                *(uint2*)&vT[((long)((bb*8 + h)*64 + d))*1024 + n] = pk.q;
            }
        }
        return;
    }

    const float qs = (MODE == 1) ? __expf(temp[0]) * 1.44269504f : 1.0f;
    const float mulv = (MODE == 1 && bn < 4) ? qs : 1.0f;   // block-uniform

#pragma unroll
    for (int i = 0; i < 4; ++i) {
        const int row0 = bm*128 + (w >> 1)*64 + i*16 + l4*4;
#pragma unroll
        for (int j = 0; j < 4; ++j) {
            const int col = bn*128 + (w & 1)*64 + j*16 + l15;
#pragma unroll
            for (int r = 0; r < 4; ++r) {
                const float v = acc[i][j][r] * mulv;
                if (MODE == 1) ((ushortT*)Cv)[(long)(row0 + r)*N + col] = f2bf(v);
                else           ((float*)Cv)[(long)(row0 + r)*N + col]   = v;
            }
        }
    }
}

// ---------------------------------------------------------------------------
// Fused flash attention, bf16 MFMA, diag mask, fixed-max softmax.
// Grid (64 bh, 8 qtiles). 256 thr = 4 waves x 32 q-rows (QBLK=128).
// Diag mask: tiles jt=2*qb / 2*qb+1 at (jt&1)*64 + j*16+l15 == lrow.
// LDS 48KB -> 3 blocks/CU. Q pre-scaled in GEMM1 (log2 domain), p=exp2(S).
// K and V staged via global_load_lds (V from pre-transposed vT),
// XOR-swizzled, double-buffered, one barrier/tile.
// P swizzle col ^ ((row>>2)&3)<<4: write cols are a per-row bijection ->
// ds_write_b16 spreads 64 lanes over 64 cols = 32 banks x 2 (free);
// b128 pa-read keeps 16B alignment (XOR is multiple of 16 elems).
// Row-sum via ones-fragment MFMA. P wave-local through LDS.
// ---------------------------------------------------------------------------
__global__ __launch_bounds__(256, 3)
void attn_mfma(const ushortT* __restrict__ qkv, const ushortT* __restrict__ vT,
               ushortT* __restrict__ aout)
{
    __shared__ ushortT Ps[128*64];      // P tile; also Q staging area (16 KB)
    __shared__ ushortT Ks[2][64*64];    // [key][d], XOR-swizzled
    __shared__ ushortT Vs[2][64*64];    // [d][key], XOR-swizzled

    const int t    = threadIdx.x;
    const int lane = t & 63;
    const int w    = t >> 6;
    const int l15  = lane & 15, l4 = lane >> 4;
    const int bh   = blockIdx.x;
    const int qb   = blockIdx.y;
    const int b    = bh >> 3, h = bh & 7;

    const long row0 = (long)b * SEQ * QKVLD;
    const char* vtb = (const char*)(vT + (long)bh * 64 * 1024);

    short8 onesf;
#pragma unroll
    for (int e = 0; e < 8; ++e) onesf[e] = (short)0x3F80;  // bf16 1.0

    // ---- prologue: stage Q (128x64) -> Ps area, K0 -> Ks[0], V0 -> Vs[0] ----
    {
        const char* qbase = (const char*)(qkv + row0 + (long)qb*128*QKVLD + h*DHEAD);
        const char* kbase = (const char*)(qkv + row0 + DMODEL + h*DHEAD);
#pragma unroll
        for (int c = 0; c < 4; ++c) {
            const int row  = c*32 + (t >> 3);
            const int scol = ((t & 7) ^ (row & 7)) << 4;
            g2l16(qbase + (long)row*(QKVLD*2) + scol, (char*)Ps + c*4096 + t*16);
        }
#pragma unroll
        for (int c = 0; c < 2; ++c) {
            const int row  = c*32 + (t >> 3);
            const int scol = ((t & 7) ^ (row & 7)) << 4;
            g2l16(kbase + (long)row*(QKVLD*2) + scol, (char*)&Ks[0][0] + c*4096 + t*16);
            g2l16(vtb + (long)row*2048 + scol,        (char*)&Vs[0][0] + c*4096 + t*16);
        }
        asm volatile("s_waitcnt vmcnt(0)" ::: "memory");
        __syncthreads();
    }

    // ---- hoist Q fragments to registers (wave-local rows: w*32 + i*16) ----
    short8 qa[2][2];
#pragma unroll
    for (int i = 0; i < 2; ++i)
#pragma unroll
    for (int kk = 0; kk < 2; ++kk) {
        const int r = w*32 + i*16 + l15;
        const int c = (kk*32 + l4*8) ^ ((r & 7) << 3);
        qa[i][kk] = *(const short8*)&Ps[r*64 + c];
    }

    f32x4 o_[2][4] = {};
    f32x4 lacc[2]  = {};

    for (int jt = 0; jt < 16; ++jt) {
        const int cur = jt & 1, nxt = cur ^ 1;
        const bool pf = (jt + 1) < 16;

        // ---- prefetch next tile: K and V via global_load_lds ----
        if (pf) {
            const char* kbase = (const char*)(qkv + row0 + (long)(jt+1)*64*QKVLD
                                              + DMODEL + h*DHEAD);
#pragma unroll
            for (int c = 0; c < 2; ++c) {
                const int row  = c*32 + (t >> 3);
                const int scol = ((t & 7) ^ (row & 7)) << 4;
                g2l16(kbase + (long)row*(QKVLD*2) + scol,
                      (char*)&Ks[nxt][0] + c*4096 + t*16);
                g2l16(vtb + (long)row*2048 + (jt+1)*128 + scol,
                      (char*)&Vs[nxt][0] + c*4096 + t*16);
            }
        }

        // ---- S = Q K^T (wave: 32 rows x 64 keys), log2 domain already ----
        f32x4 s_[2][4] = {};
#pragma unroll
        for (int kk = 0; kk < 2; ++kk) {
            short8 kb[4];
#pragma unroll
            for (int j = 0; j < 4; ++j) {
                const int r = j*16 + l15;
                const int c = (kk*32 + l4*8) ^ ((r & 7) << 3);
                kb[j] = *(const short8*)&Ks[cur][r*64 + c];
            }
#pragma unroll
            for (int i = 0; i < 2; ++i)
#pragma unroll
            for (int j = 0; j < 4; ++j)
                s_[i][j] = __builtin_amdgcn_mfma_f32_16x16x32_bf16(
                               qa[i][kk], kb[j], s_[i][j], 0, 0, 0);
        }

        // ---- fixed-max softmax: per-lane; diag mask on the two diag tiles ----
        if ((jt >> 1) == qb) {
            const int coff = (jt & 1) << 6;   // 0 or 64: col offset in block rows
#pragma unroll
            for (int i = 0; i < 2; ++i)
#pragma unroll
            for (int r = 0; r < 4; ++r) {
                const int lrow = w*32 + i*16 + l4*4 + r;
#pragma unroll
                for (int j = 0; j < 4; ++j) {
                    float p = exp2f(s_[i][j][r]);
                    if (coff + j*16 + l15 == lrow) p = 0.f;   // true diagonal
                    Ps[lrow*64 + ((j*16 + l15) ^ (((lrow >> 2) & 3) << 4))] = f2bf_fast(p);
                }
            }
        } else {
#pragma unroll
            for (int i = 0; i < 2; ++i)
#pragma unroll
            for (int r = 0; r < 4; ++r) {
                const int lrow = w*32 + i*16 + l4*4 + r;
#pragma unroll
                for (int j = 0; j < 4; ++j) {
                    const float p = exp2f(s_[i][j][r]);
                    Ps[lrow*64 + ((j*16 + l15) ^ (((lrow >> 2) & 3) << 4))] = f2bf_fast(p);
                }
            }
        }
        // P is wave-local: no barrier; compiler orders ds_write->ds_read.

        // ---- O += P V ; l += P . 1 (ones-fragment MFMA) ----
#pragma unroll
        for (int kk = 0; kk < 2; ++kk) {
            short8 pa[2];
#pragma unroll
            for (int i = 0; i < 2; ++i) {
                const int rp = w*32 + i*16 + l15;
                const int cp = (kk*32 + l4*8) ^ (((rp >> 2) & 3) << 4);
                pa[i] = *(const short8*)&Ps[rp*64 + cp];
                lacc[i] = __builtin_amdgcn_mfma_f32_16x16x32_bf16(
                              pa[i], onesf, lacc[i], 0, 0, 0);
            }
            short8 vb[4];
#pragma unroll
            for (int j = 0; j < 4; ++j) {
                const int r = j*16 + l15;
                const int c = (kk*32 + l4*8) ^ ((r & 7) << 3);
                vb[j] = *(const short8*)&Vs[cur][r*64 + c];
            }
#pragma unroll
            for (int i = 0; i < 2; ++i)
#pragma unroll
            for (int j = 0; j < 4; ++j)
                o_[i][j] = __builtin_amdgcn_mfma_f32_16x16x32_bf16(
                               pa[i], vb[j], o_[i][j], 0, 0, 0);
        }

        // ---- drain prefetch, single barrier ----
        if (pf) asm volatile("s_waitcnt vmcnt(0)" ::: "memory");
        __syncthreads();
    }

    // ---- normalize + store bf16 [b*SEQ+n][h*64+d] ----
#pragma unroll
    for (int i = 0; i < 2; ++i)
#pragma unroll
    for (int r = 0; r < 4; ++r) {
        const float inv  = 1.0f / lacc[i][r];
        const long  grow = (long)b*SEQ + qb*128 + w*32 + i*16 + l4*4 + r;
#pragma unroll
        for (int j = 0; j < 4; ++j)
            aout[grow*DMODEL + h*DHEAD + j*16 + l15] = f2bf(o_[i][j][r] * inv);
    }
}

// ---------------------------------------------------------------------------
extern "C" void kernel_launch(void* const* d_in, const int* in_sizes, int n_in,
                              void* d_out, int out_size, void* d_ws, size_t ws_size,
                              hipStream_t stream)
{
    const float* x     = (const float*)d_in[0];   // [8192,512]
    const float* w_qkv = (const float*)d_in[1];   // [512,1536]
    const float* w_out = (const float*)d_in[2];   // [512,512]
    const float* temp  = (const float*)d_in[3];
    float* out = (float*)d_out;

    char* ws = (char*)d_ws;
    ushortT* x_bf   = (ushortT*)(ws);                          //  8 MB
    ushortT* wqkvT  = (ushortT*)(ws + 8388608);                //  1.5 MB
    ushortT* woutT  = (ushortT*)(ws + 9961472);                //  0.5 MB
    ushortT* qkv_bf = (ushortT*)(ws + 10485760);               // 24 MB (Q,K used)
    ushortT* vT     = (ushortT*)(ws + 35651584);               //  8 MB [b,h][d][n]
    ushortT* aout   = (ushortT*)(ws + 44040192);               //  8 MB

    // all converts in one launch
    cvt_all<<<dim3(3072), 256, 0, stream>>>(x, x_bf, w_qkv, wqkvT, w_out, woutT);

    // qkv = x @ w_qkv  (bf16; Q pre-scaled; V written transposed to vT)
    gemm_bf16<1><<<dim3(QKVLD/128, MTOT/128), 256, 0, stream>>>(
        x_bf, wqkvT, qkv_bf, vT, temp, MTOT, QKVLD, DMODEL);

    // fused attention -> aout bf16 [8192][512]
    attn_mfma<<<dim3(BATCH*NHEADS, SEQ/128), 256, 0, stream>>>(qkv_bf, vT, aout);

    // out = aout @ w_out  (fp32 out)
    gemm_bf16<0><<<dim3(DMODEL/128, MTOT/128), 256, 0, stream>>>(
        aout, woutT, out, nullptr, nullptr, MTOT, DMODEL, DMODEL);
}

// Round 9
// 135.485 us; speedup vs baseline: 1.0987x; 1.0987x over previous
//
#include <hip/hip_runtime.h>
#include <math.h>

#define BATCH  8
#define SEQ    1024
#define DMODEL 512
#define NHEADS 8
#define DHEAD  64
#define MTOT   (BATCH*SEQ)      // 8192
#define QKVLD  (3*DMODEL)       // 1536

typedef unsigned short ushortT;
typedef __attribute__((ext_vector_type(8))) short short8;
typedef __attribute__((ext_vector_type(4))) float f32x4;

typedef __attribute__((address_space(3))) unsigned char lds_byte;
typedef __attribute__((address_space(1))) const unsigned char glob_byte;

__device__ inline void g2l16(const void* g, void* l) {
    __builtin_amdgcn_global_load_lds((glob_byte*)g, (lds_byte*)l, 16, 0, 0);
}

__device__ inline ushortT f2bf(float f) {            // round-to-nearest
    union { float f; unsigned u; } v; v.f = f;
    unsigned r = (v.u + 0x7FFFu + ((v.u >> 16) & 1u)) >> 16;
    return (ushortT)r;
}
__device__ inline ushortT f2bf_fast(float f) {       // round-half-up (2 ops)
    union { float f; unsigned u; } v; v.f = f;
    return (ushortT)((v.u + 0x8000u) >> 16);
}

// ---------------------------------------------------------------------------
// All input conversions in ONE launch.
// blocks 0..2047:    x fp32 -> x_bf (8 elems/thread)
// blocks 2048..2815: w_qkv [512][1536] -> wqkvT [1536][512]
// blocks 2816..3071: w_out [512][512] -> woutT [512][512]
// ---------------------------------------------------------------------------
__global__ __launch_bounds__(256)
void cvt_all(const float* __restrict__ x, ushortT* __restrict__ x_bf,
             const float* __restrict__ Wq, ushortT* __restrict__ WqT,
             const float* __restrict__ Wo, ushortT* __restrict__ WoT)
{
    __shared__ float T[32][33];
    const int t = threadIdx.x;
    int bid = blockIdx.x;
    if (bid < 2048) {
        const int gid = bid * 256 + t;
        const float4 a = *(const float4*)(x + (long)gid*8);
        const float4 b = *(const float4*)(x + (long)gid*8 + 4);
        ushortT o[8];
        o[0]=f2bf(a.x); o[1]=f2bf(a.y); o[2]=f2bf(a.z); o[3]=f2bf(a.w);
        o[4]=f2bf(b.x); o[5]=f2bf(b.y); o[6]=f2bf(b.z); o[7]=f2bf(b.w);
        *(short8*)(x_bf + (long)gid*8) = *(short8*)o;
        return;
    }
    bid -= 2048;
    const float* W; ushortT* WT; int N, n0, k0;
    if (bid < 768) { W = Wq; WT = WqT; N = QKVLD;  n0 = (bid % 48) * 32; k0 = (bid / 48) * 32; }
    else { bid -= 768; W = Wo; WT = WoT; N = DMODEL; n0 = (bid % 16) * 32; k0 = (bid / 16) * 32; }
    const int K = DMODEL;
    {
        const int r = t >> 3, c4 = (t & 7) * 4;
        const float4 v = *(const float4*)(W + (long)(k0 + r)*N + n0 + c4);
        T[c4+0][r] = v.x; T[c4+1][r] = v.y; T[c4+2][r] = v.z; T[c4+3][r] = v.w;
    }
    __syncthreads();
    {
        const int n = t >> 3, k4 = (t & 7) * 4;
        ushortT o[4];
        o[0] = f2bf(T[n][k4+0]); o[1] = f2bf(T[n][k4+1]);
        o[2] = f2bf(T[n][k4+2]); o[3] = f2bf(T[n][k4+3]);
        *(uint2*)(WT + (long)(n0 + n)*K + k0 + k4) = *(uint2*)o;
    }
}

// ---------------------------------------------------------------------------
// bf16 MFMA GEMM: C[M][N] = A[M][K] * BT[N][K]^T   (R7-proven form)
// 128x128 tile, BK=64, 256 thr (2x2 waves), global_load_lds width-16,
// 3-bit XOR swizzle on global source + ds_read side, 3 blocks/CU.
// MODE 0: fp32 C out.
// MODE 1 (qkv): bf16 C; Q cols (bn<4) pre-scaled by exp(temp)*log2e;
//   V cols (bn>=8) written ONLY to vT[b,h][d][n] (transposed).
// ---------------------------------------------------------------------------
template <int MODE>
__global__ __launch_bounds__(256, 3)
void gemm_bf16(const ushortT* __restrict__ A, const ushortT* __restrict__ BT,
               void* __restrict__ Cv, ushortT* __restrict__ vT,
               const float* __restrict__ temp, int M, int N, int K)
{
    __shared__ ushortT As[128*64];   // 16 KB
    __shared__ ushortT Bs[128*64];   // 16 KB

    const int t    = threadIdx.x;
    const int lane = t & 63;
    const int w    = t >> 6;
    const int l15  = lane & 15, l4 = lane >> 4;

    const int nwg = gridDim.x * gridDim.y;
    const int bid = blockIdx.y * gridDim.x + blockIdx.x;
    const int swz = (bid & 7) * (nwg >> 3) + (bid >> 3);
    const int bm  = swz / gridDim.x;
    const int bn  = swz % gridDim.x;

    const int srow = t >> 3;     // 0..31
    const int slot = t & 7;      // 0..7 (16B slots in a 128B row)

    f32x4 acc[4][4] = {};

    for (int kt = 0; kt < K; kt += 64) {
#pragma unroll
        for (int c = 0; c < 4; ++c) {
            const int row  = c*32 + srow;
            const int scol = ((slot ^ (row & 7)) << 4);   // bytes
            g2l16((const char*)(A  + (long)(bm*128 + row)*K + kt) + scol,
                  (char*)As + c*4096 + t*16);
            g2l16((const char*)(BT + (long)(bn*128 + row)*K + kt) + scol,
                  (char*)Bs + c*4096 + t*16);
        }
        asm volatile("s_waitcnt vmcnt(0)" ::: "memory");
        __syncthreads();

#pragma unroll
        for (int kk = 0; kk < 2; ++kk) {
            short8 a[4], b[4];
#pragma unroll
            for (int i = 0; i < 4; ++i) {
                const int ra = (w >> 1)*64 + i*16 + l15;
                const int ca = (kk*32 + l4*8) ^ ((ra & 7) << 3);
                a[i] = *(const short8*)&As[ra*64 + ca];
                const int rb = (w & 1)*64 + i*16 + l15;
                const int cb = (kk*32 + l4*8) ^ ((rb & 7) << 3);
                b[i] = *(const short8*)&Bs[rb*64 + cb];
            }
#pragma unroll
            for (int i = 0; i < 4; ++i)
#pragma unroll
                for (int j = 0; j < 4; ++j)
                    acc[i][j] = __builtin_amdgcn_mfma_f32_16x16x32_bf16(
                                    a[i], b[j], acc[i][j], 0, 0, 0);
        }
        __syncthreads();
    }

    if (MODE == 1 && bn >= 8) {
        // V columns -> vT[(b*8+h)*64 + d][n], packed 4x bf16 along n
#pragma unroll
        for (int i = 0; i < 4; ++i) {
            const int row0 = bm*128 + (w >> 1)*64 + i*16 + l4*4;
            const int bb   = row0 >> 10, n = row0 & 1023;
#pragma unroll
            for (int j = 0; j < 4; ++j) {
                const int cg = bn*128 + (w & 1)*64 + j*16 + l15 - 1024; // 0..511
                const int h = cg >> 6, d = cg & 63;
                union { ushortT u[4]; uint2 q; } pk;
#pragma unroll
                for (int r = 0; r < 4; ++r) pk.u[r] = f2bf(acc[i][j][r]);
                *(uint2*)&vT[((long)((bb*8 + h)*64 + d))*1024 + n] = pk.q;
            }
        }
        return;
    }

    const float qs = (MODE == 1) ? __expf(temp[0]) * 1.44269504f : 1.0f;
    const float mulv = (MODE == 1 && bn < 4) ? qs : 1.0f;   // block-uniform

#pragma unroll
    for (int i = 0; i < 4; ++i) {
        const int row0 = bm*128 + (w >> 1)*64 + i*16 + l4*4;
#pragma unroll
        for (int j = 0; j < 4; ++j) {
            const int col = bn*128 + (w & 1)*64 + j*16 + l15;
#pragma unroll
            for (int r = 0; r < 4; ++r) {
                const float v = acc[i][j][r] * mulv;
                if (MODE == 1) ((ushortT*)Cv)[(long)(row0 + r)*N + col] = f2bf(v);
                else           ((float*)Cv)[(long)(row0 + r)*N + col]   = v;
            }
        }
    }
}

// ---------------------------------------------------------------------------
// Fused flash attention, bf16 MFMA, diag mask, fixed-max softmax.
// Grid (64 bh, 8 qtiles). *** 512 thr = 8 waves x 16 q-rows *** (QBLK=128).
// TLP fix: attn was latency-bound (MfmaUtil 14 / VALU 34 / DS ~35 / Occ 17
// -- nothing saturated) at 8 waves/CU; 512-thr blocks double to 16 waves/CU
// at the same grid(512), LDS(48KB->2 blocks/CU), and total LDS traffic.
// P swizzle: R7-proven ((row&7)<<3) (0 conflicts measured; R8's variant
// regressed). Diag mask: tiles jt=2*qb/2*qb+1 at (jt&1)*64+j*16+l15==lrow.
// Q pre-scaled in GEMM1 (log2 domain), p=exp2(S). K,V staged via
// global_load_lds (V from pre-transposed vT), XOR-swizzled, double-buffered,
// one barrier/tile. Row-sum via ones-fragment MFMA. P wave-local in LDS.
// ---------------------------------------------------------------------------
__global__ __launch_bounds__(512, 4)
void attn_mfma(const ushortT* __restrict__ qkv, const ushortT* __restrict__ vT,
               ushortT* __restrict__ aout)
{
    __shared__ ushortT Ps[128*64];      // P tile; also Q staging area (16 KB)
    __shared__ ushortT Ks[2][64*64];    // [key][d], XOR-swizzled
    __shared__ ushortT Vs[2][64*64];    // [d][key], XOR-swizzled

    const int t    = threadIdx.x;       // 0..511
    const int lane = t & 63;
    const int w    = t >> 6;            // 0..7
    const int l15  = lane & 15, l4 = lane >> 4;
    const int bh   = blockIdx.x;
    const int qb   = blockIdx.y;
    const int b    = bh >> 3, h = bh & 7;

    const long row0 = (long)b * SEQ * QKVLD;
    const char* vtb = (const char*)(vT + (long)bh * 64 * 1024);

    short8 onesf;
#pragma unroll
    for (int e = 0; e < 8; ++e) onesf[e] = (short)0x3F80;  // bf16 1.0

    // ---- prologue: stage Q (128x64) -> Ps, K0 -> Ks[0], V0 -> Vs[0] ----
    {
        const char* qbase = (const char*)(qkv + row0 + (long)qb*128*QKVLD + h*DHEAD);
        const char* kbase = (const char*)(qkv + row0 + DMODEL + h*DHEAD);
        // Q: 16KB = 2 calls x 512 thr x 16B
#pragma unroll
        for (int c = 0; c < 2; ++c) {
            const int idx  = c*512 + t;
            const int row  = idx >> 3;              // 0..127
            const int scol = ((idx & 7) ^ (row & 7)) << 4;
            g2l16(qbase + (long)row*(QKVLD*2) + scol, (char*)Ps + c*8192 + t*16);
        }
        // K,V: 8KB each = 1 call x 512 thr x 16B
        {
            const int row  = t >> 3;                // 0..63
            const int scol = ((t & 7) ^ (row & 7)) << 4;
            g2l16(kbase + (long)row*(QKVLD*2) + scol, (char*)&Ks[0][0] + t*16);
            g2l16(vtb + (long)row*2048 + scol,        (char*)&Vs[0][0] + t*16);
        }
        asm volatile("s_waitcnt vmcnt(0)" ::: "memory");
        __syncthreads();
    }

    // ---- hoist Q fragments to registers (wave-local rows: w*16 + l15) ----
    short8 qa[2];
#pragma unroll
    for (int kk = 0; kk < 2; ++kk) {
        const int r = w*16 + l15;
        const int c = (kk*32 + l4*8) ^ ((r & 7) << 3);
        qa[kk] = *(const short8*)&Ps[r*64 + c];
    }

    f32x4 o_[4] = {};
    f32x4 lacc  = {};

    for (int jt = 0; jt < 16; ++jt) {
        const int cur = jt & 1, nxt = cur ^ 1;
        const bool pf = (jt + 1) < 16;

        // ---- prefetch next tile: K and V via global_load_lds ----
        if (pf) {
            const char* kbase = (const char*)(qkv + row0 + (long)(jt+1)*64*QKVLD
                                              + DMODEL + h*DHEAD);
            const int row  = t >> 3;
            const int scol = ((t & 7) ^ (row & 7)) << 4;
            g2l16(kbase + (long)row*(QKVLD*2) + scol, (char*)&Ks[nxt][0] + t*16);
            g2l16(vtb + (long)row*2048 + (jt+1)*128 + scol, (char*)&Vs[nxt][0] + t*16);
        }

        // ---- S = Q K^T (wave: 16 rows x 64 keys), log2 domain already ----
        f32x4 s_[4] = {};
#pragma unroll
        for (int kk = 0; kk < 2; ++kk) {
            short8 kb[4];
#pragma unroll
            for (int j = 0; j < 4; ++j) {
                const int r = j*16 + l15;
                const int c = (kk*32 + l4*8) ^ ((r & 7) << 3);
                kb[j] = *(const short8*)&Ks[cur][r*64 + c];
            }
#pragma unroll
            for (int j = 0; j < 4; ++j)
                s_[j] = __builtin_amdgcn_mfma_f32_16x16x32_bf16(
                            qa[kk], kb[j], s_[j], 0, 0, 0);
        }

        // ---- fixed-max softmax: per-lane; diag mask on the two diag tiles ----
        if ((jt >> 1) == qb) {
            const int coff = (jt & 1) << 6;   // 0 or 64
#pragma unroll
            for (int r = 0; r < 4; ++r) {
                const int lrow = w*16 + l4*4 + r;
#pragma unroll
                for (int j = 0; j < 4; ++j) {
                    float p = exp2f(s_[j][r]);
                    if (coff + j*16 + l15 == lrow) p = 0.f;   // true diagonal
                    Ps[lrow*64 + ((j*16 + l15) ^ ((lrow & 7) << 3))] = f2bf_fast(p);
                }
            }
        } else {
#pragma unroll
            for (int r = 0; r < 4; ++r) {
                const int lrow = w*16 + l4*4 + r;
#pragma unroll
                for (int j = 0; j < 4; ++j) {
                    const float p = exp2f(s_[j][r]);
                    Ps[lrow*64 + ((j*16 + l15) ^ ((lrow & 7) << 3))] = f2bf_fast(p);
                }
            }
        }
        // P is wave-local: no barrier; compiler orders ds_write->ds_read.

        // ---- O += P V ; l += P . 1 (ones-fragment MFMA) ----
#pragma unroll
        for (int kk = 0; kk < 2; ++kk) {
            const int rp = w*16 + l15;
            const int cp = (kk*32 + l4*8) ^ ((rp & 7) << 3);
            const short8 pa = *(const short8*)&Ps[rp*64 + cp];
            lacc = __builtin_amdgcn_mfma_f32_16x16x32_bf16(pa, onesf, lacc, 0, 0, 0);
            short8 vb[4];
#pragma unroll
            for (int j = 0; j < 4; ++j) {
                const int r = j*16 + l15;
                const int c = (kk*32 + l4*8) ^ ((r & 7) << 3);
                vb[j] = *(const short8*)&Vs[cur][r*64 + c];
            }
#pragma unroll
            for (int j = 0; j < 4; ++j)
                o_[j] = __builtin_amdgcn_mfma_f32_16x16x32_bf16(
                            pa, vb[j], o_[j], 0, 0, 0);
        }

        // ---- drain prefetch, single barrier ----
        if (pf) asm volatile("s_waitcnt vmcnt(0)" ::: "memory");
        __syncthreads();
    }

    // ---- normalize + store bf16 [b*SEQ+n][h*64+d] ----
#pragma unroll
    for (int r = 0; r < 4; ++r) {
        const float inv  = 1.0f / lacc[r];
        const long  grow = (long)b*SEQ + qb*128 + w*16 + l4*4 + r;
#pragma unroll
        for (int j = 0; j < 4; ++j)
            aout[grow*DMODEL + h*DHEAD + j*16 + l15] = f2bf(o_[j][r] * inv);
    }
}

// ---------------------------------------------------------------------------
extern "C" void kernel_launch(void* const* d_in, const int* in_sizes, int n_in,
                              void* d_out, int out_size, void* d_ws, size_t ws_size,
                              hipStream_t stream)
{
    const float* x     = (const float*)d_in[0];   // [8192,512]
    const float* w_qkv = (const float*)d_in[1];   // [512,1536]
    const float* w_out = (const float*)d_in[2];   // [512,512]
    const float* temp  = (const float*)d_in[3];
    float* out = (float*)d_out;

    char* ws = (char*)d_ws;
    ushortT* x_bf   = (ushortT*)(ws);                          //  8 MB
    ushortT* wqkvT  = (ushortT*)(ws + 8388608);                //  1.5 MB
    ushortT* woutT  = (ushortT*)(ws + 9961472);                //  0.5 MB
    ushortT* qkv_bf = (ushortT*)(ws + 10485760);               // 24 MB (Q,K used)
    ushortT* vT     = (ushortT*)(ws + 35651584);               //  8 MB [b,h][d][n]
    ushortT* aout   = (ushortT*)(ws + 44040192);               //  8 MB

    // all converts in one launch
    cvt_all<<<dim3(3072), 256, 0, stream>>>(x, x_bf, w_qkv, wqkvT, w_out, woutT);

    // qkv = x @ w_qkv  (bf16; Q pre-scaled; V written transposed to vT)
    gemm_bf16<1><<<dim3(QKVLD/128, MTOT/128), 256, 0, stream>>>(
        x_bf, wqkvT, qkv_bf, vT, temp, MTOT, QKVLD, DMODEL);

    // fused attention -> aout bf16 [8192][512]  (512 threads, 8 waves)
    attn_mfma<<<dim3(BATCH*NHEADS, SEQ/128), 512, 0, stream>>>(qkv_bf, vT, aout);

    // out = aout @ w_out  (fp32 out)
    gemm_bf16<0><<<dim3(DMODEL/128, MTOT/128), 256, 0, stream>>>(
        aout, woutT, out, nullptr, nullptr, MTOT, DMODEL, DMODEL);
}